// Round 12
// baseline (158.707 us; speedup 1.0000x reference)
//
#include <hip/hip_runtime.h>
#include <math.h>

// B=2, C=O=256, H=W=64, K=33 offsets (D=4 rings).
typedef __attribute__((ext_vector_type(4))) float f4;

__device__ __forceinline__ int iclamp(int x, int lo, int hi) { return min(max(x, lo), hi); }

// Offsets sorted row-major (dx, then dy); permutation consistent across
// aff / softmax-mask / out, so softmax result is unchanged.
__device__ constexpr int DXS[33] = {-4,-4,-4, -3,-3,-3, -2,-2,-2, -1,-1,-1,
                                     0,0,0,0,0,0,0,0,0,
                                     1,1,1, 2,2,2, 3,3,3, 4,4,4};
__device__ constexpr int DYS[33] = {-4,0,4, -3,0,3, -2,0,2, -1,0,1,
                                    -4,-3,-2,-1,0,1,2,3,4,
                                    -1,0,1, -2,0,2, -3,0,3, -4,0,4};

// ---------------------------------------------------------------------------
// GEMM (split-K 2): Epart[kz] = sum_{c in kz's 128} W[o][c]*X[b][c][p]
// (+bias for kz=0). 128x128 tile, 8x8 acc. grid (32 n, 2 m, 8 = kz*4+gb)
// = 512 blocks = 2 blocks/CU = 8 waves/CU (R11: 256 blocks -> 4 waves/CU,
// Occupancy 9.7%, grid-starved at 60 us vs 20.6 us LDS floor).
// (256,1): 512-VGPR ceiling, no 128-notch spill (R8: 458 MB scratch).
// Halves are summed inside aff_part staging (E's only consumer).
// ---------------------------------------------------------------------------
__global__ __launch_bounds__(256, 1) void gemm_f32(
    const float* __restrict__ Wf, const float* __restrict__ bf,
    const float* __restrict__ Wg, const float* __restrict__ bg,
    const float* __restrict__ Ft, const float* __restrict__ FtE,
    float* __restrict__ Ef, float* __restrict__ Eg)
{
    __shared__ float As[2][16][132];   // [c][o] transposed, pad 132
    __shared__ float Bs[2][16][128];   // [c][p]

    const int z = blockIdx.z;
    const int gb = z & 3, kz = z >> 2;          // kz = K-half
    const int g = gb >> 1, b = gb & 1;
    const float* Wmat = g ? Wg : Wf;
    const float* bias = g ? bg : bf;
    const float* X = (g ? FtE : Ft) + (size_t)b * 256 * 4096;
    // E layout: [kz][b][o][p] per matrix (halves contiguous)
    float* E = (g ? Eg : Ef) + (size_t)kz * 2 * 256 * 4096 + (size_t)b * 256 * 4096;

    const int tid = threadIdx.x;
    const int tn = tid & 15, tm = tid >> 4;
    const int m0 = blockIdx.y * 128, n0 = blockIdx.x * 128;
    const int k0 = kz * 128;

    float acc[8][8] = {};
    f4 areg[2], breg[2];

    auto loadG = [&](int kk) {
        #pragma unroll
        for (int i = 0; i < 2; ++i) {
            int f = i * 256 + tid;
            areg[i] = *(const f4*)&Wmat[(size_t)(m0 + (f >> 2)) * 256 + kk + (f & 3) * 4];
            breg[i] = *(const f4*)&X[(size_t)(kk + (f >> 5)) * 4096 + n0 + (f & 31) * 4];
        }
    };
    auto storeL = [&](int buf) {
        #pragma unroll
        for (int i = 0; i < 2; ++i) {
            int f = i * 256 + tid;
            int o = f >> 2, cq = f & 3;
            As[buf][cq * 4 + 0][o] = areg[i].x;
            As[buf][cq * 4 + 1][o] = areg[i].y;
            As[buf][cq * 4 + 2][o] = areg[i].z;
            As[buf][cq * 4 + 3][o] = areg[i].w;
            *(f4*)&Bs[buf][f >> 5][(f & 31) * 4] = breg[i];
        }
    };

    loadG(k0); storeL(0);
    __syncthreads();

    for (int ch = 0; ch < 8; ++ch) {            // 8 chunks of 16 = K half
        const int buf = ch & 1;
        if (ch < 7) loadG(k0 + (ch + 1) * 16);
        #pragma unroll
        for (int k = 0; k < 16; ++k) {
            f4 a0 = *(const f4*)&As[buf][k][tm * 8];
            f4 a1 = *(const f4*)&As[buf][k][tm * 8 + 4];
            f4 b0 = *(const f4*)&Bs[buf][k][tn * 4];
            f4 b1 = *(const f4*)&Bs[buf][k][64 + tn * 4];
            #pragma unroll
            for (int ii = 0; ii < 4; ++ii)
                #pragma unroll
                for (int jj = 0; jj < 4; ++jj) {
                    acc[ii][jj]         += a0[ii] * b0[jj];
                    acc[ii][4 + jj]     += a0[ii] * b1[jj];
                    acc[4 + ii][jj]     += a1[ii] * b0[jj];
                    acc[4 + ii][4 + jj] += a1[ii] * b1[jj];
                }
        }
        if (ch < 7) storeL(buf ^ 1);
        __syncthreads();
    }

    #pragma unroll
    for (int r = 0; r < 8; ++r) {
        int o = m0 + tm * 8 + r;
        float bvs = (kz == 0) ? bias[o] : 0.f;   // bias once
        f4 v0 = { acc[r][0] + bvs, acc[r][1] + bvs, acc[r][2] + bvs, acc[r][3] + bvs };
        f4 v1 = { acc[r][4] + bvs, acc[r][5] + bvs, acc[r][6] + bvs, acc[r][7] + bvs };
        *(f4*)&E[(size_t)o * 4096 + n0 + tn * 4] = v0;
        *(f4*)&E[(size_t)o * 4096 + n0 + 64 + tn * 4] = v1;
    }
}

// ---------------------------------------------------------------------------
// aff_part: part[cseg][b][k][p] = sum_{c in cseg's 16} Eg[c,p]*Ef[c,p+off_k]
// Sums the two split-K halves during staging (vef0+vef1 -> LDS).
// 4-row h-strips, 1 px/thread, aff[33] in regs, (256,1) spill-proof.
// grid (16 strips, 2 b, 16 cseg) = 512 blocks.
// ---------------------------------------------------------------------------
__global__ __launch_bounds__(256, 1) void aff_part(
    const float* __restrict__ Ef, const float* __restrict__ Eg,
    float* __restrict__ part)
{
    __shared__ float Lef[2][4][12][72];  // [buf][ch][hrow 12=4+8halo][72 w-halo]
    __shared__ float Leg[2][4][4][64];   // [buf][ch][strip row][w]

    const int strip = blockIdx.x, b = blockIdx.y, cseg = blockIdx.z;
    const int h0 = strip * 4, c0 = cseg * 16;
    const int tid = threadIdx.x;
    const int hs = tid >> 6, w = tid & 63;    // hs wave-uniform
    const int h = h0 + hs, p = h * 64 + w;
    const size_t plane = (size_t)b * 256 * 4096;
    const size_t half = (size_t)2 * 256 * 4096;   // kz stride
    const float* Ef0 = Ef + plane;
    const float* Ef1 = Ef + half + plane;
    const float* Eg0 = Eg + plane;
    const float* Eg1 = Eg + half + plane;

    f4 vef0[3], vef1[3], veg0, veg1; float sed0[2], sed1[2];

    auto load_rnd = [&](int rnd) {
        const int c0r = c0 + rnd * 4;
        #pragma unroll
        for (int i = 0; i < 3; ++i) {          // 768 f4 interior
            int idx = i * 256 + tid;
            int ch = idx / 192, rem = idx % 192, rr = rem >> 4, c4 = rem & 15;
            int hrow = iclamp(h0 - 4 + rr, 0, 63);
            size_t off = (size_t)(c0r + ch) * 4096 + hrow * 64 + c4 * 4;
            vef0[i] = *(const f4*)&Ef0[off];
            vef1[i] = *(const f4*)&Ef1[off];
        }
        {                                       // 256 f4 Eg strip rows
            int ch = tid >> 6, rem = tid & 63, rr = rem >> 4, c4 = rem & 15;
            size_t off = (size_t)(c0r + ch) * 4096 + (h0 + rr) * 64 + c4 * 4;
            veg0 = *(const f4*)&Eg0[off];
            veg1 = *(const f4*)&Eg1[off];
        }
        #pragma unroll
        for (int i = 0; i < 2; ++i) {          // 384 edge scalars
            int e = i * 256 + tid;
            if (e < 384) {
                int row = e >> 3, sc = e & 7, ch = row / 12, rr = row % 12;
                int hrow = iclamp(h0 - 4 + rr, 0, 63);
                int wsrc = (sc < 4) ? 0 : 63;
                size_t off = (size_t)(c0r + ch) * 4096 + hrow * 64 + wsrc;
                sed0[i] = Ef0[off];
                sed1[i] = Ef1[off];
            }
        }
    };
    auto store_rnd = [&](int buf) {
        #pragma unroll
        for (int i = 0; i < 3; ++i) {
            int idx = i * 256 + tid;
            int ch = idx / 192, rem = idx % 192, rr = rem >> 4, c4 = rem & 15;
            f4 s = vef0[i] + vef1[i];
            *(f4*)&Lef[buf][ch][rr][4 + c4 * 4] = s;
        }
        {
            int ch = tid >> 6, rem = tid & 63, rr = rem >> 4, c4 = rem & 15;
            f4 s = veg0 + veg1;
            *(f4*)&Leg[buf][ch][rr][c4 * 4] = s;
        }
        #pragma unroll
        for (int i = 0; i < 2; ++i) {
            int e = i * 256 + tid;
            if (e < 384) {
                int row = e >> 3, sc = e & 7, ch = row / 12, rr = row % 12;
                int col = (sc < 4) ? sc : (64 + sc);
                Lef[buf][ch][rr][col] = sed0[i] + sed1[i];
            }
        }
    };

    float aff[33];
    #pragma unroll
    for (int k = 0; k < 33; ++k) aff[k] = 0.f;

    load_rnd(0); store_rnd(0);
    __syncthreads();
    for (int rnd = 0; rnd < 4; ++rnd) {
        if (rnd < 3) load_rnd(rnd + 1);
        const int buf = rnd & 1;
        #pragma unroll
        for (int ch = 0; ch < 4; ++ch) {
            float eg = Leg[buf][ch][hs][w];
            #pragma unroll
            for (int k = 0; k < 33; ++k)
                aff[k] += eg * Lef[buf][ch][hs + 4 + DXS[k]][4 + w + DYS[k]];
        }
        if (rnd < 3) store_rnd(buf ^ 1);
        __syncthreads();
    }

    float* pB = part + (((size_t)cseg * 2 + b) * 33) * 4096 + p;
    #pragma unroll
    for (int k = 0; k < 33; ++k) pB[(size_t)k * 4096] = aff[k];
}

// ---------------------------------------------------------------------------
// softmax_k: per pixel sum 16 partials, mask invalid -> -inf, softmax, write
// wgt[b][k][p]. 128 blocks x 64.
// ---------------------------------------------------------------------------
__global__ __launch_bounds__(64, 1) void softmax_k(
    const float* __restrict__ part, float* __restrict__ wgt)
{
    const int id = blockIdx.x * 64 + threadIdx.x;
    const int b = id >> 12, p = id & 4095;
    const int h = p >> 6, w = p & 63;

    float a[33];
    float m = -INFINITY;
    #pragma unroll
    for (int k = 0; k < 33; ++k) {
        float s = 0.f;
        #pragma unroll
        for (int seg = 0; seg < 16; ++seg)
            s += part[(((size_t)seg * 2 + b) * 33 + k) * 4096 + p];
        bool valid = ((unsigned)(h + DXS[k]) < 64u) && ((unsigned)(w + DYS[k]) < 64u);
        a[k] = valid ? s : -INFINITY;
        m = fmaxf(m, a[k]);
    }
    float ssum = 0.f;
    #pragma unroll
    for (int k = 0; k < 33; ++k) { float e = __expf(a[k] - m); a[k] = e; ssum += e; }
    float inv = 1.0f / ssum;
    float* wgtB = wgt + (size_t)b * 33 * 4096 + p;
    #pragma unroll
    for (int k = 0; k < 33; ++k) wgtB[(size_t)k * 4096] = a[k] * inv;
}

// ---------------------------------------------------------------------------
// out: out[c][p] = sum_k wgt[k,p]*Ft[c,p+off_k]. Strip skeleton, (256,1).
// grid (16,2,16) = 512 blocks, 1 px/thread.
// Invalid k has wgt==0 -> clamped gather contributes 0.
// ---------------------------------------------------------------------------
__global__ __launch_bounds__(256, 1) void out_kernel(
    const float* __restrict__ wgt, const float* __restrict__ Ft,
    float* __restrict__ out)
{
    __shared__ float Lft[2][4][12][72];

    const int strip = blockIdx.x, b = blockIdx.y, cseg = blockIdx.z;
    const int h0 = strip * 4, c0 = cseg * 16;
    const int tid = threadIdx.x;
    const int hs = tid >> 6, w = tid & 63;
    const int h = h0 + hs, p = h * 64 + w;
    const size_t plane = (size_t)b * 256 * 4096;
    const float* FtB = Ft + plane;
    float* outB = out + plane;

    const float* wgtB = wgt + (size_t)b * 33 * 4096 + p;
    float wv[33];
    #pragma unroll
    for (int k = 0; k < 33; ++k) wv[k] = wgtB[(size_t)k * 4096];

    f4 vef[3]; float sed[2];

    auto load_rnd = [&](int rnd) {
        const int c0r = c0 + rnd * 4;
        #pragma unroll
        for (int i = 0; i < 3; ++i) {
            int idx = i * 256 + tid;
            int ch = idx / 192, rem = idx % 192, rr = rem >> 4, c4 = rem & 15;
            int hrow = iclamp(h0 - 4 + rr, 0, 63);
            vef[i] = *(const f4*)&FtB[(size_t)(c0r + ch) * 4096 + hrow * 64 + c4 * 4];
        }
        #pragma unroll
        for (int i = 0; i < 2; ++i) {
            int e = i * 256 + tid;
            if (e < 384) {
                int row = e >> 3, sc = e & 7, ch = row / 12, rr = row % 12;
                int hrow = iclamp(h0 - 4 + rr, 0, 63);
                int wsrc = (sc < 4) ? 0 : 63;
                sed[i] = FtB[(size_t)(c0r + ch) * 4096 + hrow * 64 + wsrc];
            }
        }
    };
    auto store_rnd = [&](int buf) {
        #pragma unroll
        for (int i = 0; i < 3; ++i) {
            int idx = i * 256 + tid;
            int ch = idx / 192, rem = idx % 192, rr = rem >> 4, c4 = rem & 15;
            *(f4*)&Lft[buf][ch][rr][4 + c4 * 4] = vef[i];
        }
        #pragma unroll
        for (int i = 0; i < 2; ++i) {
            int e = i * 256 + tid;
            if (e < 384) {
                int row = e >> 3, sc = e & 7, ch = row / 12, rr = row % 12;
                int col = (sc < 4) ? sc : (64 + sc);
                Lft[buf][ch][rr][col] = sed[i];
            }
        }
    };

    load_rnd(0); store_rnd(0);
    __syncthreads();
    for (int rnd = 0; rnd < 4; ++rnd) {
        if (rnd < 3) load_rnd(rnd + 1);
        const int buf = rnd & 1;
        #pragma unroll
        for (int ch = 0; ch < 4; ++ch) {
            float o = 0.f;
            #pragma unroll
            for (int k = 0; k < 33; ++k)
                o += wv[k] * Lft[buf][ch][hs + 4 + DXS[k]][4 + w + DYS[k]];
            outB[(size_t)(c0 + rnd * 4 + ch) * 4096 + p] = o;
        }
        if (rnd < 3) store_rnd(buf ^ 1);
        __syncthreads();
    }
}

// ---------------------------------------------------------------------------
extern "C" void kernel_launch(void* const* d_in, const int* in_sizes, int n_in,
                              void* d_out, int out_size, void* d_ws, size_t ws_size,
                              hipStream_t stream) {
    const float* Ft  = (const float*)d_in[0];
    const float* FtE = (const float*)d_in[1];
    const float* Wf  = (const float*)d_in[2];
    const float* bf  = (const float*)d_in[3];
    const float* Wg  = (const float*)d_in[4];
    const float* bg  = (const float*)d_in[5];
    float* out = (float*)d_out;

    // ws: Ef [2kz][2b][256][4096] 16.8MB | Eg same 16.8MB |
    //     part [16][2][33][4096] 17.3MB | wgt 1.1MB  (~52 MB total)
    float* Ef  = (float*)d_ws;
    float* Eg  = Ef + (size_t)2 * 2 * 256 * 4096;
    float* part = Eg + (size_t)2 * 2 * 256 * 4096;
    float* wgt = part + (size_t)16 * 2 * 33 * 4096;

    hipLaunchKernelGGL(gemm_f32, dim3(32, 2, 8), dim3(256), 0, stream,
                       Wf, bf, Wg, bg, Ft, FtE, Ef, Eg);
    hipLaunchKernelGGL(aff_part, dim3(16, 2, 16), dim3(256), 0, stream,
                       Ef, Eg, part);
    hipLaunchKernelGGL(softmax_k, dim3(128), dim3(64), 0, stream,
                       part, wgt);
    hipLaunchKernelGGL(out_kernel, dim3(16, 2, 16), dim3(256), 0, stream,
                       wgt, Ft, out);
}